// Round 1
// baseline (466.747 us; speedup 1.0000x reference)
//
#include <hip/hip_runtime.h>
#include <hip/hip_cooperative_groups.h>
#include <stdint.h>
#include <math.h>

namespace cg = cooperative_groups;

// Native 16-byte vector type — __builtin_nontemporal_{load,store} requires a
// native vector, not HIP's float4 class.
typedef float vf4 __attribute__((ext_vector_type(4)));

__device__ __forceinline__ void mm4(vf4 v, float& mn, float& mx) {
    mn = fminf(mn, fminf(fminf(v.x, v.y), fminf(v.z, v.w)));
    mx = fmaxf(mx, fmaxf(fmaxf(v.x, v.y), fmaxf(v.z, v.w)));
}

__device__ __forceinline__ vf4 q4(vf4 v, float mn, float scale, float inv_scale) {
    vf4 r;
    r.x = rintf((v.x - mn) * scale) * inv_scale + mn;
    r.y = rintf((v.y - mn) * scale) * inv_scale + mn;
    r.z = rintf((v.z - mn) * scale) * inv_scale + mn;
    r.w = rintf((v.w - mn) * scale) * inv_scale + mn;
    return r;
}

// ---------------------------------------------------------------------------
// Fused single-dispatch path (cooperative launch).
//   Phase 1: grid-stride min/max, block partial -> ws[bid], ws[nb+bid]
//            (plain stores: no atomics, no init kernel, no init bubble)
//   grid.sync()  (device-scope barrier+fence: partials visible cross-XCD)
//   Phase 2: every block reduces the nb partials (<=16 KB, L2-resident),
//            then quantizes its own chunk. Input re-read hits L3 (205 MB
//            < 256 MB Infinity Cache); output streamed with NT stores so
//            write-allocate doesn't evict the input from L3.
// __launch_bounds__(256, 4): >=4 blocks/CU guaranteed co-resident; actual
// grid chosen from the occupancy API so cooperative launch can't oversubscribe.
// ---------------------------------------------------------------------------
__global__ __launch_bounds__(256, 4) void fused_fakequant(
    const float* __restrict__ x, long n,
    float* __restrict__ o,
    float* __restrict__ ws)
{
    const vf4* __restrict__ x4 = (const vf4*)x;
    vf4* __restrict__ o4 = (vf4*)o;
    const unsigned n4 = (unsigned)(n >> 2);

    cg::grid_group grid = cg::this_grid();
    const unsigned bs = blockDim.x;      // 256
    const unsigned nb = gridDim.x;
    const unsigned tid = threadIdx.x;

    // ---- Phase 1: local min/max (4x unrolled, independent accumulators) ----
    float mn0 = INFINITY, mn1 = INFINITY, mn2 = INFINITY, mn3 = INFINITY;
    float mx0 = -INFINITY, mx1 = -INFINITY, mx2 = -INFINITY, mx3 = -INFINITY;

    const unsigned stride = nb * bs * 4u;
    unsigned base = blockIdx.x * bs * 4u + tid;
    for (; base + 3u * bs < n4; base += stride) {
        vf4 v0 = x4[base];
        vf4 v1 = x4[base + bs];
        vf4 v2 = x4[base + 2u * bs];
        vf4 v3 = x4[base + 3u * bs];
        mm4(v0, mn0, mx0);
        mm4(v1, mn1, mx1);
        mm4(v2, mn2, mx2);
        mm4(v3, mn3, mx3);
    }
    for (; base < n4; base += bs) mm4(x4[base], mn0, mx0);
    // scalar tail (n % 4 != 0) — not hit for this shape, kept for generality
    for (long i = (long)n4 * 4 + (long)blockIdx.x * bs + tid; i < n;
         i += (long)nb * bs) {
        float v = x[i];
        mn0 = fminf(mn0, v); mx0 = fmaxf(mx0, v);
    }

    float mn = fminf(fminf(mn0, mn1), fminf(mn2, mn3));
    float mx = fmaxf(fmaxf(mx0, mx1), fmaxf(mx2, mx3));
    #pragma unroll
    for (int off = 32; off > 0; off >>= 1) {
        mn = fminf(mn, __shfl_down(mn, off, 64));
        mx = fmaxf(mx, __shfl_down(mx, off, 64));
    }
    __shared__ float smn[4], smx[4];
    const int wave = tid >> 6;
    const int lane = tid & 63;
    if (lane == 0) { smn[wave] = mn; smx[wave] = mx; }
    __syncthreads();
    if (tid == 0) {
        ws[blockIdx.x]      = fminf(fminf(smn[0], smn[1]), fminf(smn[2], smn[3]));
        ws[nb + blockIdx.x] = fmaxf(fmaxf(smx[0], smx[1]), fmaxf(smx[2], smx[3]));
    }

    grid.sync();   // all partials written & device-visible past this point

    // ---- Phase 2: reduce partials (every block, ~8 values/thread max) ----
    float gmn = INFINITY, gmx = -INFINITY;
    for (unsigned i = tid; i < nb; i += bs) {
        gmn = fminf(gmn, ws[i]);
        gmx = fmaxf(gmx, ws[nb + i]);
    }
    #pragma unroll
    for (int off = 32; off > 0; off >>= 1) {
        gmn = fminf(gmn, __shfl_down(gmn, off, 64));
        gmx = fmaxf(gmx, __shfl_down(gmx, off, 64));
    }
    // grid.sync() was a full barrier, so reusing smn/smx is safe here
    if (lane == 0) { smn[wave] = gmn; smx[wave] = gmx; }
    __syncthreads();
    const float fmn = fminf(fminf(smn[0], smn[1]), fminf(smn[2], smn[3]));
    const float fmx = fmaxf(fmaxf(smx[0], smx[1]), fmaxf(smx[2], smx[3]));
    const float scale = 255.0f / (fmx - fmn);
    const float inv_scale = 1.0f / scale;

    // ---- Phase 2: quantize. Same chunk as phase 1 (L3-hot). NT stores. ----
    base = blockIdx.x * bs * 4u + tid;
    for (; base + 3u * bs < n4; base += stride) {
        vf4 v0 = x4[base];
        vf4 v1 = x4[base + bs];
        vf4 v2 = x4[base + 2u * bs];
        vf4 v3 = x4[base + 3u * bs];
        __builtin_nontemporal_store(q4(v0, fmn, scale, inv_scale), &o4[base]);
        __builtin_nontemporal_store(q4(v1, fmn, scale, inv_scale), &o4[base + bs]);
        __builtin_nontemporal_store(q4(v2, fmn, scale, inv_scale), &o4[base + 2u * bs]);
        __builtin_nontemporal_store(q4(v3, fmn, scale, inv_scale), &o4[base + 3u * bs]);
    }
    for (; base < n4; base += bs)
        __builtin_nontemporal_store(q4(x4[base], fmn, scale, inv_scale), &o4[base]);
    for (long i = (long)n4 * 4 + (long)blockIdx.x * bs + tid; i < n;
         i += (long)nb * bs)
        o[i] = rintf((x[i] - fmn) * scale) * inv_scale + fmn;
}

// ---------------------------------------------------------------------------
// Fallback path (previous best 3-kernel structure) — used only if cooperative
// launch is unavailable or the workspace can't hold 2*grid floats.
// ---------------------------------------------------------------------------
__device__ __forceinline__ uint32_t enc_f32(float f) {
    uint32_t b = __float_as_uint(f);
    return (b & 0x80000000u) ? ~b : (b | 0x80000000u);
}
__device__ __forceinline__ float dec_f32(uint32_t u) {
    uint32_t b = (u & 0x80000000u) ? (u ^ 0x80000000u) : ~u;
    return __uint_as_float(b);
}

__global__ void init_ws_kernel(uint32_t* ws) {
    ws[0] = 0xFFFFFFFFu;
    ws[1] = 0x00000000u;
}

__global__ __launch_bounds__(256) void minmax_kernel(
    const vf4* __restrict__ x4, unsigned n4,
    uint32_t* __restrict__ ws)
{
    float mn0 = INFINITY, mn1 = INFINITY, mn2 = INFINITY, mn3 = INFINITY;
    float mx0 = -INFINITY, mx1 = -INFINITY, mx2 = -INFINITY, mx3 = -INFINITY;

    const unsigned bs = blockDim.x;
    const unsigned stride = gridDim.x * bs * 4u;
    unsigned base = blockIdx.x * bs * 4u + threadIdx.x;

    for (; base + 3u * bs < n4; base += stride) {
        vf4 v0 = x4[base];
        vf4 v1 = x4[base + bs];
        vf4 v2 = x4[base + 2u * bs];
        vf4 v3 = x4[base + 3u * bs];
        mm4(v0, mn0, mx0);
        mm4(v1, mn1, mx1);
        mm4(v2, mn2, mx2);
        mm4(v3, mn3, mx3);
    }
    for (; base < n4; base += bs) mm4(x4[base], mn0, mx0);

    float mn = fminf(fminf(mn0, mn1), fminf(mn2, mn3));
    float mx = fmaxf(fmaxf(mx0, mx1), fmaxf(mx2, mx3));
    #pragma unroll
    for (int off = 32; off > 0; off >>= 1) {
        mn = fminf(mn, __shfl_down(mn, off, 64));
        mx = fmaxf(mx, __shfl_down(mx, off, 64));
    }
    __shared__ float smn[4], smx[4];
    const int wave = threadIdx.x >> 6;
    const int lane = threadIdx.x & 63;
    if (lane == 0) { smn[wave] = mn; smx[wave] = mx; }
    __syncthreads();
    if (threadIdx.x == 0) {
        mn = fminf(fminf(smn[0], smn[1]), fminf(smn[2], smn[3]));
        mx = fmaxf(fmaxf(smx[0], smx[1]), fmaxf(smx[2], smx[3]));
        atomicMin(&ws[0], enc_f32(mn));
        atomicMax(&ws[1], enc_f32(mx));
    }
}

__global__ __launch_bounds__(256) void quant_kernel(
    const vf4* __restrict__ x4, unsigned n4,
    vf4* __restrict__ o4,
    const uint32_t* __restrict__ ws)
{
    const float mn = dec_f32(ws[0]);
    const float mx = dec_f32(ws[1]);
    const float scale = 255.0f / (mx - mn);
    const float inv_scale = 1.0f / scale;

    const unsigned bs = blockDim.x;
    const unsigned stride = gridDim.x * bs * 4u;
    unsigned base = blockIdx.x * bs * 4u + threadIdx.x;

    for (; base + 3u * bs < n4; base += stride) {
        vf4 v0 = x4[base];
        vf4 v1 = x4[base + bs];
        vf4 v2 = x4[base + 2u * bs];
        vf4 v3 = x4[base + 3u * bs];
        __builtin_nontemporal_store(q4(v0, mn, scale, inv_scale), &o4[base]);
        __builtin_nontemporal_store(q4(v1, mn, scale, inv_scale), &o4[base + bs]);
        __builtin_nontemporal_store(q4(v2, mn, scale, inv_scale), &o4[base + 2u * bs]);
        __builtin_nontemporal_store(q4(v3, mn, scale, inv_scale), &o4[base + 3u * bs]);
    }
    for (; base < n4; base += bs)
        __builtin_nontemporal_store(q4(x4[base], mn, scale, inv_scale), &o4[base]);
}

__global__ void quant_tail_kernel(const float* __restrict__ x, long start, long n,
                                  float* __restrict__ o,
                                  const uint32_t* __restrict__ ws)
{
    const float mn = dec_f32(ws[0]);
    const float mx = dec_f32(ws[1]);
    const float scale = 255.0f / (mx - mn);
    const float inv_scale = 1.0f / scale;
    long i = start + threadIdx.x;
    if (i < n) o[i] = rintf((x[i] - mn) * scale) * inv_scale + mn;
}

__global__ void minmax_tail_kernel(const float* __restrict__ x, long start, long n,
                                   uint32_t* __restrict__ ws)
{
    long i = start + threadIdx.x;
    if (i < n) {
        float v = x[i];
        atomicMin(&ws[0], enc_f32(v));
        atomicMax(&ws[1], enc_f32(v));
    }
}

extern "C" void kernel_launch(void* const* d_in, const int* in_sizes, int n_in,
                              void* d_out, int out_size, void* d_ws, size_t ws_size,
                              hipStream_t stream) {
    const float* x = (const float*)d_in[0];
    float* out = (float*)d_out;
    const long n = (long)in_sizes[0];
    const unsigned n4 = (unsigned)(n / 4);

    // One-time host-side setup (no stream ops: graph-capture safe).
    // Occupancy query guarantees the cooperative grid is co-resident.
    static int coop_grid = -2;
    if (coop_grid == -2) {
        coop_grid = -1;
        hipDeviceProp_t props;
        int dev = 0;
        if (hipGetDevice(&dev) == hipSuccess &&
            hipGetDeviceProperties(&props, dev) == hipSuccess &&
            props.cooperativeLaunch) {
            int maxb = 0;
            if (hipOccupancyMaxActiveBlocksPerMultiprocessor(
                    &maxb, (const void*)fused_fakequant, 256, 0) == hipSuccess &&
                maxb > 0) {
                long g = (long)maxb * props.multiProcessorCount;
                if (g > 2048) g = 2048;   // ~6+ iters of 64 B/thread at this size
                coop_grid = (int)g;
            }
        }
    }

    if (coop_grid > 0 && ws_size >= (size_t)coop_grid * 2u * sizeof(float)) {
        float* wsf = (float*)d_ws;
        long nn = n;
        void* args[] = { (void*)&x, (void*)&nn, (void*)&out, (void*)&wsf };
        hipLaunchCooperativeKernel((void*)fused_fakequant, dim3(coop_grid),
                                   dim3(256), args, 0, stream);
        return;
    }

    // Fallback: previous best 3-kernel pipeline.
    uint32_t* ws = (uint32_t*)d_ws;
    init_ws_kernel<<<1, 1, 0, stream>>>(ws);
    const int block = 256;
    const int grid = 2048;
    minmax_kernel<<<grid, block, 0, stream>>>((const vf4*)x, n4, ws);
    if (n % 4) minmax_tail_kernel<<<1, 256, 0, stream>>>(x, (long)n4 * 4, n, ws);
    quant_kernel<<<grid, block, 0, stream>>>((const vf4*)x, n4, (vf4*)out, ws);
    if (n % 4) quant_tail_kernel<<<1, 256, 0, stream>>>(x, (long)n4 * 4, n, out, ws);
}

// Round 2
// 366.406 us; speedup vs baseline: 1.2739x; 1.2739x over previous
//
#include <hip/hip_runtime.h>
#include <stdint.h>
#include <math.h>

// Native vector types — __builtin_nontemporal_{load,store} requires a native
// vector, not HIP's float4 class.
typedef float vf4 __attribute__((ext_vector_type(4)));
typedef float vf2 __attribute__((ext_vector_type(2)));

__device__ __forceinline__ void mm4(vf4 v, float& mn, float& mx) {
    mn = fminf(mn, fminf(fminf(v.x, v.y), fminf(v.z, v.w)));
    mx = fmaxf(mx, fmaxf(fmaxf(v.x, v.y), fmaxf(v.z, v.w)));
}

__device__ __forceinline__ vf4 q4(vf4 v, float mn, float scale, float inv_scale) {
    vf4 r;
    r.x = rintf((v.x - mn) * scale) * inv_scale + mn;
    r.y = rintf((v.y - mn) * scale) * inv_scale + mn;
    r.z = rintf((v.z - mn) * scale) * inv_scale + mn;
    r.w = rintf((v.w - mn) * scale) * inv_scale + mn;
    return r;
}

// ---------------------------------------------------------------------------
// Pass 1: per-block min/max -> plain 8 B store of {min,max} into ws[bid].
// No atomics, no init kernel, no order-preserving encode. The kernel
// boundary provides the global barrier + cross-XCD visibility (round-1
// lesson: cg::grid_group::sync() costs ~200+ µs at 2048 blocks — the
// dispatch boundary is the cheap barrier).
// Plain (allocating) loads on purpose: they pull the input into the 256 MB
// Infinity Cache so pass 2's re-read doesn't touch HBM (verified round 1:
// FETCH_SIZE stayed at exactly 1x input with this access pattern).
// ---------------------------------------------------------------------------
__global__ __launch_bounds__(256) void minmax_partial(
    const float* __restrict__ x, long n,
    vf2* __restrict__ ws)
{
    const vf4* __restrict__ x4 = (const vf4*)x;
    const unsigned n4 = (unsigned)(n >> 2);

    float mn0 = INFINITY, mn1 = INFINITY, mn2 = INFINITY, mn3 = INFINITY;
    float mx0 = -INFINITY, mx1 = -INFINITY, mx2 = -INFINITY, mx3 = -INFINITY;

    const unsigned bs = blockDim.x;                 // 256
    const unsigned stride = gridDim.x * bs * 4u;    // vf4 elements per iter
    unsigned base = blockIdx.x * bs * 4u + threadIdx.x;

    // 4x unroll, independent accumulators: 4 x 16 B loads in flight per
    // thread per iteration, dest registers disjoint so the compiler keeps
    // them all outstanding (vmcnt>0 between consumes).
    for (; base + 3u * bs < n4; base += stride) {
        vf4 v0 = x4[base];
        vf4 v1 = x4[base + bs];
        vf4 v2 = x4[base + 2u * bs];
        vf4 v3 = x4[base + 3u * bs];
        mm4(v0, mn0, mx0);
        mm4(v1, mn1, mx1);
        mm4(v2, mn2, mx2);
        mm4(v3, mn3, mx3);
    }
    for (; base < n4; base += bs) mm4(x4[base], mn0, mx0);
    // Scalar tail (n % 4 != 0) — not hit for this shape, kept for generality.
    for (long i = (long)n4 * 4 + (long)blockIdx.x * bs + threadIdx.x; i < n;
         i += (long)gridDim.x * bs) {
        float v = x[i];
        mn0 = fminf(mn0, v); mx0 = fmaxf(mx0, v);
    }

    float mn = fminf(fminf(mn0, mn1), fminf(mn2, mn3));
    float mx = fmaxf(fmaxf(mx0, mx1), fmaxf(mx2, mx3));
    #pragma unroll
    for (int off = 32; off > 0; off >>= 1) {
        mn = fminf(mn, __shfl_down(mn, off, 64));
        mx = fmaxf(mx, __shfl_down(mx, off, 64));
    }
    __shared__ float smn[4], smx[4];
    const int wave = threadIdx.x >> 6;
    const int lane = threadIdx.x & 63;
    if (lane == 0) { smn[wave] = mn; smx[wave] = mx; }
    __syncthreads();
    if (threadIdx.x == 0) {
        vf2 p;
        p.x = fminf(fminf(smn[0], smn[1]), fminf(smn[2], smn[3]));
        p.y = fmaxf(fmaxf(smx[0], smx[1]), fmaxf(smx[2], smx[3]));
        ws[blockIdx.x] = p;   // plain store; kernel-end flush makes it visible
    }
}

// ---------------------------------------------------------------------------
// Pass 2: every block redundantly reduces the nb partials (nb*8 B <= 16 KB,
// L2/L3-resident after pass 1's writeback — ~1-2 µs, overlapped across
// blocks), then quantizes its chunk.
// NT stores: output is written once and never re-read; bypassing the caches
// keeps the input (L3-hot from pass 1) from being evicted by write-allocate.
// ---------------------------------------------------------------------------
__global__ __launch_bounds__(256) void quant_from_partials(
    const float* __restrict__ x, long n,
    float* __restrict__ o,
    const vf2* __restrict__ ws, unsigned nb)
{
    const vf4* __restrict__ x4 = (const vf4*)x;
    vf4* __restrict__ o4 = (vf4*)o;
    const unsigned n4 = (unsigned)(n >> 2);
    const unsigned bs = blockDim.x;
    const unsigned tid = threadIdx.x;

    // --- preamble: global min/max from partials ---
    float mn = INFINITY, mx = -INFINITY;
    for (unsigned i = tid; i < nb; i += bs) {
        vf2 p = ws[i];
        mn = fminf(mn, p.x);
        mx = fmaxf(mx, p.y);
    }
    #pragma unroll
    for (int off = 32; off > 0; off >>= 1) {
        mn = fminf(mn, __shfl_down(mn, off, 64));
        mx = fmaxf(mx, __shfl_down(mx, off, 64));
    }
    __shared__ float smn[4], smx[4];
    const int wave = tid >> 6;
    const int lane = tid & 63;
    if (lane == 0) { smn[wave] = mn; smx[wave] = mx; }
    __syncthreads();
    const float fmn = fminf(fminf(smn[0], smn[1]), fminf(smn[2], smn[3]));
    const float fmx = fmaxf(fmaxf(smx[0], smx[1]), fmaxf(smx[2], smx[3]));
    const float scale = 255.0f / (fmx - fmn);
    const float inv_scale = 1.0f / scale;

    // --- main quant loop ---
    const unsigned stride = gridDim.x * bs * 4u;
    unsigned base = blockIdx.x * bs * 4u + tid;
    for (; base + 3u * bs < n4; base += stride) {
        vf4 v0 = x4[base];
        vf4 v1 = x4[base + bs];
        vf4 v2 = x4[base + 2u * bs];
        vf4 v3 = x4[base + 3u * bs];
        __builtin_nontemporal_store(q4(v0, fmn, scale, inv_scale), &o4[base]);
        __builtin_nontemporal_store(q4(v1, fmn, scale, inv_scale), &o4[base + bs]);
        __builtin_nontemporal_store(q4(v2, fmn, scale, inv_scale), &o4[base + 2u * bs]);
        __builtin_nontemporal_store(q4(v3, fmn, scale, inv_scale), &o4[base + 3u * bs]);
    }
    for (; base < n4; base += bs)
        __builtin_nontemporal_store(q4(x4[base], fmn, scale, inv_scale), &o4[base]);
    // Scalar tail (n % 4 != 0) — not hit for this shape.
    for (long i = (long)n4 * 4 + (long)blockIdx.x * bs + tid; i < n;
         i += (long)gridDim.x * bs)
        o[i] = rintf((x[i] - fmn) * scale) * inv_scale + fmn;
}

extern "C" void kernel_launch(void* const* d_in, const int* in_sizes, int n_in,
                              void* d_out, int out_size, void* d_ws, size_t ws_size,
                              hipStream_t stream) {
    const float* x = (const float*)d_in[0];
    float* out = (float*)d_out;
    const long n = (long)in_sizes[0];

    const int block = 256;
    // 2048 blocks = 8 blocks/CU = 32 waves/CU (full occupancy); each thread
    // does ~6 iterations of 64 B. Round 1 empirically confirmed ws_size >=
    // 16 KB (the coop path required it and was taken); guard anyway.
    int grid = 2048;
    const size_t need = (size_t)grid * sizeof(vf2);
    if (ws_size < need) {
        size_t g = ws_size / sizeof(vf2);
        grid = (g < 256) ? 256 : (int)g;   // 256*8 B = 2 KB minimum
    }

    vf2* ws = (vf2*)d_ws;
    minmax_partial<<<grid, block, 0, stream>>>(x, n, ws);
    quant_from_partials<<<grid, block, 0, stream>>>(x, n, out, ws, (unsigned)grid);
}